// Round 11
// baseline (190.395 us; speedup 1.0000x reference)
//
#include <hip/hip_runtime.h>

#define N_CELL 100000
#define N_GENE 20000
#define DIM    128
#define N_EDGE 1000000

#define BINS      100352   // 98*1024 >= N_CELL, zero-padded
#define NB_SCAN   98
#define NB_EDGEB  977      // x1024 edges >= N_EDGE

// misc kernel ranges
#define NB_WCAST 8
#define NB_CTAB  391
#define NB_GTAB  79
#define NB_MISC  (NB_WCAST + NB_CTAB + NB_GTAB)

// fused prep: proj + src-histogram
#define NB_PROJ  625       // 32 gene rows each
#define NB_HIST  977
#define NB_PREP  (NB_PROJ + NB_HIST)

typedef float f32x4 __attribute__((ext_vector_type(4)));

// Round-to-nearest-even f32 -> bf16.
__device__ inline unsigned short f2bf(float f) {
    unsigned u = __float_as_uint(f);
    u += 0x7fffu + ((u >> 16) & 1u);
    return (unsigned short)(u >> 16);
}

// HW bf16 pair-dot: acc += a.lo*b.lo + a.hi*b.hi (f32 accumulate).
__device__ inline void dot2(float& acc, unsigned a, unsigned b) {
    asm("v_dot2_f32_bf16 %0, %1, %2, %0" : "+v"(acc) : "v"(a), "v"(b));
}

// bf16 pair halves as f32
#define BLO(u) __uint_as_float((u) << 16)
#define BHI(u) __uint_as_float((u) & 0xffff0000u)

// pack (src:17b, dst:15b)
__device__ inline unsigned pack_sd(int s, int d) {
    return ((unsigned)s << 15) | (unsigned)d;
}

__device__ inline float lrelu(float v) { return v > 0.f ? v : 0.01f * v; }

// ---------------------------------------------------------------------------
// misc: [0,8) W f32 -> bf16 transposed Wbt[col][k8] (uint4 of 8 k-vals);
//       [+391) cell_p4 = {scale,bias,std}[cell_n_id[c]];
//       [+79)  gene_p4 likewise.
// ---------------------------------------------------------------------------
__global__ __launch_bounds__(256) void misc_kernel(
    const float* __restrict__ W,
    ushort* __restrict__ Wbt,
    const int*   __restrict__ cell_n_id,
    const int*   __restrict__ gene_n_id,
    const float* __restrict__ cell_scale,
    const float* __restrict__ cell_bias,
    const float* __restrict__ cell_std,
    const float* __restrict__ gene_scale,
    const float* __restrict__ gene_bias,
    const float* __restrict__ gene_std,
    float4* __restrict__ cell_p4,
    float4* __restrict__ gene_p4)
{
    const int tid = threadIdx.x;
    int blk = blockIdx.x;

    if (blk < NB_WCAST) {
        const int t   = blk * 256 + tid;    // 0..2047
        const int col = t >> 4;
        const int k8  = t & 15;
        unsigned short w[8];
        #pragma unroll
        for (int j = 0; j < 8; ++j)
            w[j] = f2bf(W[(k8 * 8 + j) * DIM + col]);
        uint4 o;
        o.x = (unsigned)w[0] | ((unsigned)w[1] << 16);
        o.y = (unsigned)w[2] | ((unsigned)w[3] << 16);
        o.z = (unsigned)w[4] | ((unsigned)w[5] << 16);
        o.w = (unsigned)w[6] | ((unsigned)w[7] << 16);
        ((uint4*)Wbt)[t] = o;
        return;
    }
    blk -= NB_WCAST;

    if (blk < NB_CTAB) {
        const int c = blk * 256 + tid;
        if (c < N_CELL) {
            const int id = cell_n_id[c];
            cell_p4[c] = make_float4(cell_scale[id], cell_bias[id],
                                     cell_std[id], 0.f);
        }
        return;
    }
    blk -= NB_CTAB;

    const int g = blk * 256 + tid;
    if (g < N_GENE) {
        const int id = gene_n_id[g];
        gene_p4[g] = make_float4(gene_scale[id], gene_bias[id],
                                 gene_std[id], 0.f);
    }
}

// ---------------------------------------------------------------------------
// prep_fused: [0,625) proj (gene_proj = leaky_relu(z@W+b) -> bf16, LDS W^T
// XOR-swizzled, validated R10); [+977) src histogram via global atomics
// (bins zeroed by memsetAsync). Fused so the VALU/LDS-bound proj overlaps
// the BW/atomic-bound hist (R10 lesson: separate launches serialize).
// ---------------------------------------------------------------------------
__global__ __launch_bounds__(256) void prep_fused(
    const float* __restrict__ gene_z,
    const float* __restrict__ b,
    const ushort* __restrict__ Wbt,
    ushort* __restrict__ gene_projb,
    const int* __restrict__ src_idx,
    int* __restrict__ bins)
{
    __shared__ ushort zb[32 * DIM];     // 8 KB
    __shared__ uint4  wl[2048];         // 32 KB swizzled W^T

    const int tid = threadIdx.x;
    int blk = blockIdx.x;

    if (blk < NB_PROJ) {
        // stage W^T swizzled
        const uint4* wg = (const uint4*)Wbt;
        #pragma unroll
        for (int i = 0; i < 8; ++i) {
            const int u = i * 256 + tid;
            const int c = u >> 4, j = u & 15;
            wl[(c << 4) | (j ^ (c & 15))] = wg[u];
        }
        // stage z -> bf16
        const int row0 = blk * 32;
        const f32x4* Z4 = (const f32x4*)(gene_z + (long)row0 * DIM);
        #pragma unroll
        for (int i = 0; i < 4; ++i) {
            const int idx = i * 256 + tid;
            const f32x4 v = Z4[idx];
            ushort4 o;
            o.x = f2bf(v.x); o.y = f2bf(v.y); o.z = f2bf(v.z); o.w = f2bf(v.w);
            ((ushort4*)zb)[idx] = o;
        }
        __syncthreads();

        const int cg = tid & 31;
        const int rg = tid >> 5;

        const float4 bb = ((const float4*)b)[cg];
        float acc[4][4];
        #pragma unroll
        for (int r = 0; r < 4; ++r) {
            acc[r][0] = bb.x; acc[r][1] = bb.y;
            acc[r][2] = bb.z; acc[r][3] = bb.w;
        }

        const uint4* zr = (const uint4*)zb;
        #pragma unroll 4
        for (int k8 = 0; k8 < 16; ++k8) {
            uint4 z[4], w[4];
            #pragma unroll
            for (int r = 0; r < 4; ++r)
                z[r] = zr[(rg * 4 + r) * 16 + k8];
            #pragma unroll
            for (int c = 0; c < 4; ++c) {
                const int col = cg * 4 + c;
                w[c] = wl[(col << 4) | (k8 ^ (col & 15))];
            }
            #pragma unroll
            for (int r = 0; r < 4; ++r)
                #pragma unroll
                for (int c = 0; c < 4; ++c) {
                    dot2(acc[r][c], z[r].x, w[c].x);
                    dot2(acc[r][c], z[r].y, w[c].y);
                    dot2(acc[r][c], z[r].z, w[c].z);
                    dot2(acc[r][c], z[r].w, w[c].w);
                }
        }

        #pragma unroll
        for (int r = 0; r < 4; ++r) {
            ushort4 o;
            o.x = f2bf(lrelu(acc[r][0]));
            o.y = f2bf(lrelu(acc[r][1]));
            o.z = f2bf(lrelu(acc[r][2]));
            o.w = f2bf(lrelu(acc[r][3]));
            *(ushort4*)(gene_projb + (long)(row0 + rg * 4 + r) * DIM + cg * 4) = o;
        }
        return;
    }
    blk -= NB_PROJ;

    // ---- src histogram: 1024 edges/block, global atomics (100k bins) ----
    #pragma unroll
    for (int q = 0; q < 4; ++q) {
        const int e = blk * 1024 + q * 256 + tid;
        if (e < N_EDGE) atomicAdd(&bins[src_idx[e]], 1);
    }
}

// ---------------------------------------------------------------------------
// scan1: block = 1024 bins; in-place exclusive intra-block prefix + blocksum.
// ---------------------------------------------------------------------------
__global__ __launch_bounds__(256) void scan1_kernel(
    int* __restrict__ bins, int* __restrict__ bsum)
{
    __shared__ int sd[256];
    const int t   = blockIdx.x;
    const int tid = threadIdx.x;
    int carry = 0;
    for (int c = 0; c < 4; ++c) {
        const int idx = t * 1024 + c * 256 + tid;
        const int val = bins[idx];
        sd[tid] = val;
        __syncthreads();
        #pragma unroll
        for (int off = 1; off < 256; off <<= 1) {
            const int tmp = (tid >= off) ? sd[tid - off] : 0;
            __syncthreads();
            sd[tid] += tmp;
            __syncthreads();
        }
        const int incl = sd[tid];
        const int ctot = sd[255];
        bins[idx] = carry + incl - val;
        carry += ctot;
        __syncthreads();
    }
    if (tid == 0) bsum[t] = carry;
}

// scan2: add exclusive prefix of blocksums to each block's 1024 bins.
__global__ __launch_bounds__(256) void scan2_kernel(
    int* __restrict__ bins, const int* __restrict__ bsum)
{
    __shared__ int bs[128];
    const int t   = blockIdx.x;
    const int tid = threadIdx.x;
    if (tid < NB_SCAN) bs[tid] = bsum[tid];
    __syncthreads();
    int bp = 0;
    for (int j = 0; j < t; ++j) bp += bs[j];
    #pragma unroll
    for (int c = 0; c < 4; ++c)
        bins[t * 1024 + c * 256 + tid] += bp;
}

// ---------------------------------------------------------------------------
// scatter: pos = atomicAdd(&bins[src],1) (consumes the scan); sorted_p[pos]
// packed (src,dst); rank[e] coalesced. Order within a src-bin varies per run
// but out[e] = f(edge e) is order-independent -> output deterministic.
// ---------------------------------------------------------------------------
__global__ __launch_bounds__(256) void scatter_kernel(
    const int* __restrict__ src_idx,
    const int* __restrict__ dst_idx,
    int* __restrict__ bins,
    unsigned* __restrict__ sorted_p,
    int*      __restrict__ rank)
{
    const int tid = threadIdx.x;
    const int blk = blockIdx.x;
    #pragma unroll
    for (int c = 0; c < 4; ++c) {
        const int e = blk * 1024 + c * 256 + tid;
        if (e < N_EDGE) {
            const int s = src_idx[e];
            const int d = dst_idx[e];
            const int pos = atomicAdd(&bins[s], 1);
            sorted_p[pos] = pack_sd(s, d);
            rank[e] = pos;
        }
    }
}

// ---------------------------------------------------------------------------
// edge kernel on src-sorted stream: u = f32 row of cell_z (each row read
// ~once, sequential in sorted order -> HBM-streamed); v = bf16 gene_projb
// (5.12MB, L2-resident; the only L2-bandwidth term left: ~0.5 GB).
// 16 lanes/edge, 4 edges/group; res writes coalesced.
// ---------------------------------------------------------------------------
__global__ __launch_bounds__(256) void edge_sorted_kernel(
    const float*  __restrict__ cell_z,
    const ushort* __restrict__ gene_projb,
    const unsigned* __restrict__ sorted_p,
    const float4* __restrict__ cell_p4,
    const float4* __restrict__ gene_p4,
    float2* __restrict__ res)
{
    // bijective XCD chunk swizzle: nwg=15625, q=1953, r=1
    const int wg  = blockIdx.x;
    const int xcd = wg & 7;
    const int sub = wg >> 3;
    const int q = 15625 / 8, r = 15625 % 8;
    const int swz = ((xcd < r) ? xcd * (q + 1) : r * (q + 1) + (xcd - r) * q) + sub;

    const int tid  = threadIdx.x;
    const int lane = tid & 15;
    const int grp  = swz * 16 + (tid >> 4);

    const uint4 p = ((const uint4*)sorted_p)[grp];
    const int s0 = (int)(p.x >> 15), d0 = (int)(p.x & 0x7fffu);
    const int s1 = (int)(p.y >> 15), d1 = (int)(p.y & 0x7fffu);
    const int s2 = (int)(p.z >> 15), d2 = (int)(p.z & 0x7fffu);
    const int s3 = (int)(p.w >> 15), d3 = (int)(p.w & 0x7fffu);

    const float4* u0p = (const float4*)(cell_z + (long)s0 * DIM);
    const float4* u1p = (const float4*)(cell_z + (long)s1 * DIM);
    const float4* u2p = (const float4*)(cell_z + (long)s2 * DIM);
    const float4* u3p = (const float4*)(cell_z + (long)s3 * DIM);

    const float4 u0a = u0p[2 * lane], u0b = u0p[2 * lane + 1];
    const float4 u1a = u1p[2 * lane], u1b = u1p[2 * lane + 1];
    const float4 u2a = u2p[2 * lane], u2b = u2p[2 * lane + 1];
    const float4 u3a = u3p[2 * lane], u3b = u3p[2 * lane + 1];
    const uint4  v0  = ((const uint4*)(gene_projb + (long)d0 * DIM))[lane];
    const uint4  v1  = ((const uint4*)(gene_projb + (long)d1 * DIM))[lane];
    const uint4  v2  = ((const uint4*)(gene_projb + (long)d2 * DIM))[lane];
    const uint4  v3  = ((const uint4*)(gene_projb + (long)d3 * DIM))[lane];

    #define DOT(res_, ua, ub, vv)                                   \
        float res_ = 0.f;                                           \
        res_ = fmaf(ua.x, BLO(vv.x), res_);                         \
        res_ = fmaf(ua.y, BHI(vv.x), res_);                         \
        res_ = fmaf(ua.z, BLO(vv.y), res_);                         \
        res_ = fmaf(ua.w, BHI(vv.y), res_);                         \
        res_ = fmaf(ub.x, BLO(vv.z), res_);                         \
        res_ = fmaf(ub.y, BHI(vv.z), res_);                         \
        res_ = fmaf(ub.z, BLO(vv.w), res_);                         \
        res_ = fmaf(ub.w, BHI(vv.w), res_);
    DOT(dot0, u0a, u0b, v0)
    DOT(dot1, u1a, u1b, v1)
    DOT(dot2v, u2a, u2b, v2)
    DOT(dot3, u3a, u3b, v3)
    #undef DOT

    #define RED(d)                 \
        d += __shfl_xor(d, 1);     \
        d += __shfl_xor(d, 2);     \
        d += __shfl_xor(d, 4);     \
        d += __shfl_xor(d, 8);
    RED(dot0) RED(dot1) RED(dot2v) RED(dot3)
    #undef RED

    if (lane < 4) {
        const float dj = (lane & 2) ? ((lane & 1) ? dot3 : dot2v)
                                    : ((lane & 1) ? dot1 : dot0);
        const int sj   = (lane & 2) ? ((lane & 1) ? s3 : s2)
                                    : ((lane & 1) ? s1 : s0);
        const int djx  = (lane & 2) ? ((lane & 1) ? d3 : d2)
                                    : ((lane & 1) ? d1 : d0);
        const float4 cs = cell_p4[sj];
        const float4 gs = gene_p4[djx];
        res[grp * 4 + lane] =
            make_float2(dj * cs.x * gs.x + cs.y + gs.y, cs.z * gs.z);
    }
}

// ---------------------------------------------------------------------------
// fixup: out[e] = res[rank[e]]. Coalesced rank reads + out writes; res is
// read-only here (every XCD can cache it) -> no write-bounce.
// ---------------------------------------------------------------------------
__global__ __launch_bounds__(256) void fixup_kernel(
    const int*    __restrict__ rank,
    const float2* __restrict__ res,
    float* __restrict__ out)
{
    const int e0 = (blockIdx.x * 256 + threadIdx.x) * 4;
    if (e0 >= N_EDGE) return;
    const int4 r4 = *(const int4*)(rank + e0);
    const float2 r0 = res[r4.x];
    const float2 r1 = res[r4.y];
    const float2 r2 = res[r4.z];
    const float2 r3 = res[r4.w];
    *(float4*)(out + e0)          = make_float4(r0.x, r1.x, r2.x, r3.x);
    *(float4*)(out + N_EDGE + e0) = make_float4(r0.y, r1.y, r2.y, r3.y);
}

// ---------------------------------------------------------------------------
// Fallback unsorted edge kernel (no tables, f32 u) if ws too small.
// ---------------------------------------------------------------------------
__global__ __launch_bounds__(256) void edge_fallback(
    const float*  __restrict__ cell_z,
    const ushort* __restrict__ gene_projb,
    const int*   __restrict__ src_idx,
    const int*   __restrict__ dst_idx,
    const int*   __restrict__ cell_n_id,
    const int*   __restrict__ gene_n_id,
    const float* __restrict__ cell_scale,
    const float* __restrict__ cell_bias,
    const float* __restrict__ cell_std,
    const float* __restrict__ gene_scale,
    const float* __restrict__ gene_bias,
    const float* __restrict__ gene_std,
    float* __restrict__ out)
{
    const int tid  = threadIdx.x;
    const int lane = tid & 15;
    const int e    = blockIdx.x * 16 + (tid >> 4);

    const int s = src_idx[e];
    const int d = dst_idx[e];
    const float4* up = (const float4*)(cell_z + (long)s * DIM);
    const float4 ua = up[2 * lane], ub = up[2 * lane + 1];
    const uint4  v  = ((const uint4*)(gene_projb + (long)d * DIM))[lane];

    float dot = 0.f;
    dot = fmaf(ua.x, BLO(v.x), dot);
    dot = fmaf(ua.y, BHI(v.x), dot);
    dot = fmaf(ua.z, BLO(v.y), dot);
    dot = fmaf(ua.w, BHI(v.y), dot);
    dot = fmaf(ub.x, BLO(v.z), dot);
    dot = fmaf(ub.y, BHI(v.z), dot);
    dot = fmaf(ub.z, BLO(v.w), dot);
    dot = fmaf(ub.w, BHI(v.w), dot);

    dot += __shfl_xor(dot, 1);
    dot += __shfl_xor(dot, 2);
    dot += __shfl_xor(dot, 4);
    dot += __shfl_xor(dot, 8);

    if (lane == 0) {
        const int sid = cell_n_id[s];
        const int did = gene_n_id[d];
        out[e]          = dot * cell_scale[sid] * gene_scale[did]
                        + cell_bias[sid] + gene_bias[did];
        out[N_EDGE + e] = cell_std[sid] * gene_std[did];
    }
}

extern "C" void kernel_launch(void* const* d_in, const int* in_sizes, int n_in,
                              void* d_out, int out_size, void* d_ws, size_t ws_size,
                              hipStream_t stream) {
    const float* cell_z     = (const float*)d_in[0];
    const float* gene_z     = (const float*)d_in[1];
    const float* W_gene     = (const float*)d_in[2];
    const float* b_gene     = (const float*)d_in[3];
    const float* cell_scale = (const float*)d_in[4];
    const float* cell_bias  = (const float*)d_in[5];
    const float* cell_std   = (const float*)d_in[6];
    const float* gene_scale = (const float*)d_in[7];
    const float* gene_bias  = (const float*)d_in[8];
    const float* gene_std   = (const float*)d_in[9];
    const int*   src_idx    = (const int*)d_in[10];
    const int*   dst_idx    = (const int*)d_in[11];
    const int*   cell_n_id  = (const int*)d_in[12];
    const int*   gene_n_id  = (const int*)d_in[13];

    // Workspace layout (~23.6 MB total):
    char* ws = (char*)d_ws;
    size_t off = 0;
    ushort* gene_projb = (ushort*)(ws + off); off += (size_t)N_GENE * DIM * 2;  // 5.12 MB
    ushort* Wbt        = (ushort*)(ws + off); off += (size_t)DIM * DIM * 2;     // 32 KB
    float4* cell_p4    = (float4*)(ws + off); off += (size_t)N_CELL * 16;       // 1.6 MB
    float4* gene_p4    = (float4*)(ws + off); off += (size_t)N_GENE * 16;       // 0.32 MB
    unsigned* sorted_p = (unsigned*)(ws + off); off += (size_t)N_EDGE * 4;      // 4 MB
    int*    rank       = (int*)(ws + off);    off += (size_t)N_EDGE * 4;        // 4 MB
    float2* res        = (float2*)(ws + off); off += (size_t)N_EDGE * 8;        // 8 MB
    int*    bins       = (int*)(ws + off);    off += (size_t)BINS * 4;          // 401 KB
    int*    bsum       = (int*)(ws + off);    off += 512;

    float* out = (float*)d_out;
    const bool ok = (ws_size >= off);

    if (!ok) {
        // minimal correct path: proj via misc(Wbt)+prep needs ws for
        // gene_projb+Wbt only (5.15 MB) — assume at least that much.
        misc_kernel<<<NB_MISC, 256, 0, stream>>>(
            W_gene, Wbt, cell_n_id, gene_n_id,
            cell_scale, cell_bias, cell_std,
            gene_scale, gene_bias, gene_std,
            (float4*)Wbt, (float4*)Wbt);  // tabs unused in fallback; harmless dummy? no:
        // (tabs would alias Wbt; instead skip tabs by launching only proj+hist-free path)
        prep_fused<<<NB_PROJ, 256, 0, stream>>>(
            gene_z, b_gene, Wbt, gene_projb, src_idx, nullptr);
        edge_fallback<<<N_EDGE / 16, 256, 0, stream>>>(
            cell_z, gene_projb, src_idx, dst_idx, cell_n_id, gene_n_id,
            cell_scale, cell_bias, cell_std,
            gene_scale, gene_bias, gene_std, out);
        return;
    }

    hipMemsetAsync(bins, 0, (size_t)BINS * 4, stream);
    misc_kernel<<<NB_MISC, 256, 0, stream>>>(
        W_gene, Wbt, cell_n_id, gene_n_id,
        cell_scale, cell_bias, cell_std,
        gene_scale, gene_bias, gene_std, cell_p4, gene_p4);
    prep_fused<<<NB_PREP, 256, 0, stream>>>(
        gene_z, b_gene, Wbt, gene_projb, src_idx, bins);
    scan1_kernel<<<NB_SCAN, 256, 0, stream>>>(bins, bsum);
    scan2_kernel<<<NB_SCAN, 256, 0, stream>>>(bins, bsum);
    scatter_kernel<<<NB_EDGEB, 256, 0, stream>>>(
        src_idx, dst_idx, bins, sorted_p, rank);
    edge_sorted_kernel<<<N_EDGE / 64, 256, 0, stream>>>(
        cell_z, gene_projb, sorted_p, cell_p4, gene_p4, res);
    fixup_kernel<<<(N_EDGE / 4 + 255) / 256, 256, 0, stream>>>(rank, res, out);
}

// Round 12
// 85.844 us; speedup vs baseline: 2.2179x; 2.2179x over previous
//
#include <hip/hip_runtime.h>

#define N_CELL 100000
#define N_GENE 20000
#define DIM    128
#define N_EDGE 1000000

// --- sort geometry: 20 src-stripes x 2 dst-stripes = 40 tiles (R8-proven) --
#define NS_STRIPE 20
#define NTILE     40
#define NBLK_SORT 977            // x1024 edges >= N_EDGE

// misc kernel ranges (Wbt must precede prep_fused's proj)
#define NB_WCAST 8
#define NB_CTAB  391
#define NB_GTAB  79
#define NB_MISC  (NB_WCAST + NB_CTAB + NB_GTAB)

// prep_fused ranges: proj (long, first) | hist | cast (short, drain tail)
#define NB_PROJ  625       // 32 gene rows each
#define NB_HIST  977
#define NB_CAST  6250
#define NB_PREP  (NB_PROJ + NB_HIST + NB_CAST)

// edge kernel: 8 edges per 16-lane group, 128 edges/block
#define NGRP     125000
#define NB_EDGE  7813      // ceil(125000/16)

typedef float f32x4 __attribute__((ext_vector_type(4)));

// Round-to-nearest-even f32 -> bf16.
__device__ inline unsigned short f2bf(float f) {
    unsigned u = __float_as_uint(f);
    u += 0x7fffu + ((u >> 16) & 1u);
    return (unsigned short)(u >> 16);
}

// HW bf16 pair-dot: acc += a.lo*b.lo + a.hi*b.hi (f32 accumulate).
__device__ inline void dot2(float& acc, unsigned a, unsigned b) {
    asm("v_dot2_f32_bf16 %0, %1, %2, %0" : "+v"(acc) : "v"(a), "v"(b));
}

__device__ inline int tile_of(int s, int d) {
    const int ss = (int)(((unsigned long long)s * 429497ULL) >> 31);  // s/5000
    const int ds = (d >= 10000) ? 1 : 0;
    return ds * NS_STRIPE + ss;
}

__device__ inline unsigned pack_sd(int s, int d) {
    return ((unsigned)s << 15) | (unsigned)d;
}

__device__ inline float lrelu(float v) { return v > 0.f ? v : 0.01f * v; }

// ---------------------------------------------------------------------------
// misc: [0,8) W f32 -> bf16 transposed Wbt[col][k8]; [+391) cell_p4 table;
// [+79) gene_p4 table. Runs before prep_fused (proj depends on Wbt).
// ---------------------------------------------------------------------------
__global__ __launch_bounds__(256) void misc_kernel(
    const float* __restrict__ W,
    ushort* __restrict__ Wbt,
    const int*   __restrict__ cell_n_id,
    const int*   __restrict__ gene_n_id,
    const float* __restrict__ cell_scale,
    const float* __restrict__ cell_bias,
    const float* __restrict__ cell_std,
    const float* __restrict__ gene_scale,
    const float* __restrict__ gene_bias,
    const float* __restrict__ gene_std,
    float4* __restrict__ cell_p4,
    float4* __restrict__ gene_p4)
{
    const int tid = threadIdx.x;
    int blk = blockIdx.x;

    if (blk < NB_WCAST) {
        const int t   = blk * 256 + tid;    // 0..2047
        const int col = t >> 4;
        const int k8  = t & 15;
        unsigned short w[8];
        #pragma unroll
        for (int j = 0; j < 8; ++j)
            w[j] = f2bf(W[(k8 * 8 + j) * DIM + col]);
        uint4 o;
        o.x = (unsigned)w[0] | ((unsigned)w[1] << 16);
        o.y = (unsigned)w[2] | ((unsigned)w[3] << 16);
        o.z = (unsigned)w[4] | ((unsigned)w[5] << 16);
        o.w = (unsigned)w[6] | ((unsigned)w[7] << 16);
        ((uint4*)Wbt)[t] = o;
        return;
    }
    blk -= NB_WCAST;

    if (blk < NB_CTAB) {
        const int c = blk * 256 + tid;
        if (c < N_CELL) {
            const int id = cell_n_id[c];
            cell_p4[c] = make_float4(cell_scale[id], cell_bias[id],
                                     cell_std[id], 0.f);
        }
        return;
    }
    blk -= NB_CTAB;

    const int g = blk * 256 + tid;
    if (g < N_GENE) {
        const int id = gene_n_id[g];
        gene_p4[g] = make_float4(gene_scale[id], gene_bias[id],
                                 gene_std[id], 0.f);
    }
}

// ---------------------------------------------------------------------------
// prep_fused (one dispatch -> phases overlap; R10 showed separate launches
// serialize on the stream):
//   [0,625)   proj: gene_proj = leaky_relu(z@W+b) -> bf16. LDS z (8KB) +
//             XOR-swizzled W^T (32KB); thread = 4 rows x 4 cols; per k8:
//             8 ds_read_b128 + 64 v_dot2 (fixes old proj's LDS-pipe bound).
//   [+977)    hist: 40-tile histogram (R8-proven).
//   [+6250)   cast: cell_z f32 -> bf16, 2 float4/thread.
// ---------------------------------------------------------------------------
__global__ __launch_bounds__(256) void prep_fused(
    const float* __restrict__ gene_z,
    const float* __restrict__ b,
    const ushort* __restrict__ Wbt,
    ushort* __restrict__ gene_projb,
    const float* __restrict__ cell_z,
    ushort4* __restrict__ cell_zb4,
    const int* __restrict__ src_idx,
    const int* __restrict__ dst_idx,
    int* __restrict__ counts)
{
    __shared__ ushort zb[32 * DIM];     // 8 KB (proj); hist aliases as int*
    __shared__ uint4  wl[2048];         // 32 KB swizzled W^T (proj only)

    const int tid = threadIdx.x;
    int blk = blockIdx.x;

    if (blk < NB_PROJ) {
        // stage W^T swizzled
        const uint4* wg = (const uint4*)Wbt;
        #pragma unroll
        for (int i = 0; i < 8; ++i) {
            const int u = i * 256 + tid;
            const int c = u >> 4, j = u & 15;
            wl[(c << 4) | (j ^ (c & 15))] = wg[u];
        }
        // stage z -> bf16
        const int row0 = blk * 32;
        const f32x4* Z4 = (const f32x4*)(gene_z + (long)row0 * DIM);
        #pragma unroll
        for (int i = 0; i < 4; ++i) {
            const int idx = i * 256 + tid;
            const f32x4 v = Z4[idx];
            ushort4 o;
            o.x = f2bf(v.x); o.y = f2bf(v.y); o.z = f2bf(v.z); o.w = f2bf(v.w);
            ((ushort4*)zb)[idx] = o;
        }
        __syncthreads();

        const int cg = tid & 31;
        const int rg = tid >> 5;

        const float4 bb = ((const float4*)b)[cg];
        float acc[4][4];
        #pragma unroll
        for (int r = 0; r < 4; ++r) {
            acc[r][0] = bb.x; acc[r][1] = bb.y;
            acc[r][2] = bb.z; acc[r][3] = bb.w;
        }

        const uint4* zr = (const uint4*)zb;
        #pragma unroll 4
        for (int k8 = 0; k8 < 16; ++k8) {
            uint4 z[4], w[4];
            #pragma unroll
            for (int r = 0; r < 4; ++r)
                z[r] = zr[(rg * 4 + r) * 16 + k8];
            #pragma unroll
            for (int c = 0; c < 4; ++c) {
                const int col = cg * 4 + c;
                w[c] = wl[(col << 4) | (k8 ^ (col & 15))];
            }
            #pragma unroll
            for (int r = 0; r < 4; ++r)
                #pragma unroll
                for (int c = 0; c < 4; ++c) {
                    dot2(acc[r][c], z[r].x, w[c].x);
                    dot2(acc[r][c], z[r].y, w[c].y);
                    dot2(acc[r][c], z[r].z, w[c].z);
                    dot2(acc[r][c], z[r].w, w[c].w);
                }
        }

        #pragma unroll
        for (int r = 0; r < 4; ++r) {
            ushort4 o;
            o.x = f2bf(lrelu(acc[r][0]));
            o.y = f2bf(lrelu(acc[r][1]));
            o.z = f2bf(lrelu(acc[r][2]));
            o.w = f2bf(lrelu(acc[r][3]));
            *(ushort4*)(gene_projb + (long)(row0 + rg * 4 + r) * DIM + cg * 4) = o;
        }
        return;
    }
    blk -= NB_PROJ;

    if (blk < NB_HIST) {
        int* lcnt = (int*)zb;
        if (tid < NTILE) lcnt[tid] = 0;
        __syncthreads();
        #pragma unroll
        for (int q = 0; q < 4; ++q) {
            const int e = blk * 1024 + q * 256 + tid;
            if (e < N_EDGE) {
                const int t = tile_of(src_idx[e], dst_idx[e]);
                atomicAdd(&lcnt[t], 1);
            }
        }
        __syncthreads();
        if (tid < NTILE) counts[tid * NBLK_SORT + blk] = lcnt[tid];
        return;
    }
    blk -= NB_HIST;

    // ---- cast: cell_z f32 -> bf16, 2 float4 per thread ----
    const f32x4* in4 = (const f32x4*)cell_z;
    const int base = blk * 512 + tid;
    const f32x4 v0 = in4[base];
    const f32x4 v1 = in4[base + 256];
    ushort4 o0, o1;
    o0.x = f2bf(v0.x); o0.y = f2bf(v0.y); o0.z = f2bf(v0.z); o0.w = f2bf(v0.w);
    o1.x = f2bf(v1.x); o1.y = f2bf(v1.y); o1.z = f2bf(v1.z); o1.w = f2bf(v1.w);
    cell_zb4[base]       = o0;
    cell_zb4[base + 256] = o1;
}

// ---------------------------------------------------------------------------
// scanA: per tile, exclusive-scan its 977 per-block counts; emit tile total.
// ---------------------------------------------------------------------------
__global__ __launch_bounds__(256) void scanA_kernel(
    int* __restrict__ counts, int* __restrict__ totals)
{
    __shared__ int sd[256];
    const int t   = blockIdx.x;
    const int tid = threadIdx.x;
    int carry = 0;
    for (int c = 0; c < 4; ++c) {
        const int idx = c * 256 + tid;
        const int val = (idx < NBLK_SORT) ? counts[t * NBLK_SORT + idx] : 0;
        sd[tid] = val;
        __syncthreads();
        #pragma unroll
        for (int off = 1; off < 256; off <<= 1) {
            const int tmp = (tid >= off) ? sd[tid - off] : 0;
            __syncthreads();
            sd[tid] += tmp;
            __syncthreads();
        }
        const int incl = sd[tid];
        const int ctot = sd[255];
        if (idx < NBLK_SORT) counts[t * NBLK_SORT + idx] = carry + incl - val;
        carry += ctot;
        __syncthreads();
    }
    if (tid == 0) totals[t] = carry;
}

// ---------------------------------------------------------------------------
// scatter (R8-proven): LDS-local rank -> 40 contiguous runs per block;
// rank[e] written coalesced in e-order.
// ---------------------------------------------------------------------------
__global__ __launch_bounds__(256) void scatter_kernel(
    const int* __restrict__ src_idx,
    const int* __restrict__ dst_idx,
    const int* __restrict__ counts,
    const int* __restrict__ totals,
    unsigned* __restrict__ sorted_p,
    int*      __restrict__ rank)
{
    __shared__ int lcnt[NTILE];
    __shared__ int sbase[NTILE];
    __shared__ int lbase[NTILE];
    const int tid = threadIdx.x;
    const int blk = blockIdx.x;
    if (tid < NTILE) lcnt[tid] = 0;
    __syncthreads();

    int ts[4], rs[4], ss[4], ds[4];
    #pragma unroll
    for (int c = 0; c < 4; ++c) {
        const int e = blk * 1024 + c * 256 + tid;
        if (e < N_EDGE) {
            ss[c] = src_idx[e];
            ds[c] = dst_idx[e];
            ts[c] = tile_of(ss[c], ds[c]);
            rs[c] = atomicAdd(&lcnt[ts[c]], 1);
        } else { ts[c] = -1; rs[c] = 0; ss[c] = 0; ds[c] = 0; }
    }
    __syncthreads();
    if (tid == 0) {
        int s = 0;
        for (int i = 0; i < NTILE; ++i) { sbase[i] = s; s += totals[i]; }
    }
    __syncthreads();
    if (tid < NTILE) lbase[tid] = sbase[tid] + counts[tid * NBLK_SORT + blk];
    __syncthreads();

    #pragma unroll
    for (int c = 0; c < 4; ++c) {
        const int e = blk * 1024 + c * 256 + tid;
        if (ts[c] >= 0) {
            const int pos = lbase[ts[c]] + rs[c];
            sorted_p[pos] = pack_sd(ss[c], ds[c]);
            rank[e] = pos;
        }
    }
}

// ---------------------------------------------------------------------------
// Sorted edge kernel: 16 lanes/edge, EIGHT edges/group (2x MLP vs R8:
// 16 row-gathers in flight before compute). res writes coalesced.
// XCD-chunk swizzle keeps each XCD in one contiguous sorted range.
// ---------------------------------------------------------------------------
__global__ __launch_bounds__(256) void edge_sorted_kernel(
    const ushort* __restrict__ cell_zb,
    const ushort* __restrict__ gene_projb,
    const unsigned* __restrict__ sorted_p,
    const float4* __restrict__ cell_p4,
    const float4* __restrict__ gene_p4,
    float2* __restrict__ res)
{
    // bijective XCD chunk swizzle: nwg=7813, q=976, r=5
    const int wg  = blockIdx.x;
    const int xcd = wg & 7;
    const int sub = wg >> 3;
    const int q = NB_EDGE / 8, r = NB_EDGE % 8;
    const int swz = ((xcd < r) ? xcd * (q + 1) : r * (q + 1) + (xcd - r) * q) + sub;

    const int tid  = threadIdx.x;
    const int lane = tid & 15;
    const int grp  = swz * 16 + (tid >> 4);
    if (grp >= NGRP) return;

    const uint4 pa = ((const uint4*)sorted_p)[grp * 2];
    const uint4 pb = ((const uint4*)sorted_p)[grp * 2 + 1];
    const int s0 = (int)(pa.x >> 15), d0 = (int)(pa.x & 0x7fffu);
    const int s1 = (int)(pa.y >> 15), d1 = (int)(pa.y & 0x7fffu);
    const int s2 = (int)(pa.z >> 15), d2 = (int)(pa.z & 0x7fffu);
    const int s3 = (int)(pa.w >> 15), d3 = (int)(pa.w & 0x7fffu);
    const int s4 = (int)(pb.x >> 15), d4 = (int)(pb.x & 0x7fffu);
    const int s5 = (int)(pb.y >> 15), d5 = (int)(pb.y & 0x7fffu);
    const int s6 = (int)(pb.z >> 15), d6 = (int)(pb.z & 0x7fffu);
    const int s7 = (int)(pb.w >> 15), d7 = (int)(pb.w & 0x7fffu);

    // 16 row gathers issued back-to-back
    const uint4 a0 = ((const uint4*)(cell_zb + (long)s0 * DIM))[lane];
    const uint4 a1 = ((const uint4*)(cell_zb + (long)s1 * DIM))[lane];
    const uint4 a2 = ((const uint4*)(cell_zb + (long)s2 * DIM))[lane];
    const uint4 a3 = ((const uint4*)(cell_zb + (long)s3 * DIM))[lane];
    const uint4 a4 = ((const uint4*)(cell_zb + (long)s4 * DIM))[lane];
    const uint4 a5 = ((const uint4*)(cell_zb + (long)s5 * DIM))[lane];
    const uint4 a6 = ((const uint4*)(cell_zb + (long)s6 * DIM))[lane];
    const uint4 a7 = ((const uint4*)(cell_zb + (long)s7 * DIM))[lane];
    const uint4 v0 = ((const uint4*)(gene_projb + (long)d0 * DIM))[lane];
    const uint4 v1 = ((const uint4*)(gene_projb + (long)d1 * DIM))[lane];
    const uint4 v2 = ((const uint4*)(gene_projb + (long)d2 * DIM))[lane];
    const uint4 v3 = ((const uint4*)(gene_projb + (long)d3 * DIM))[lane];
    const uint4 v4 = ((const uint4*)(gene_projb + (long)d4 * DIM))[lane];
    const uint4 v5 = ((const uint4*)(gene_projb + (long)d5 * DIM))[lane];
    const uint4 v6 = ((const uint4*)(gene_projb + (long)d6 * DIM))[lane];
    const uint4 v7 = ((const uint4*)(gene_projb + (long)d7 * DIM))[lane];

    float t0 = 0.f, t1 = 0.f, t2 = 0.f, t3 = 0.f;
    float t4 = 0.f, t5 = 0.f, t6 = 0.f, t7 = 0.f;
    #define D4(acc, aa, vv)                 \
        dot2(acc, aa.x, vv.x); dot2(acc, aa.y, vv.y); \
        dot2(acc, aa.z, vv.z); dot2(acc, aa.w, vv.w);
    D4(t0, a0, v0) D4(t1, a1, v1) D4(t2, a2, v2) D4(t3, a3, v3)
    D4(t4, a4, v4) D4(t5, a5, v5) D4(t6, a6, v6) D4(t7, a7, v7)
    #undef D4

    #define RED(d)                 \
        d += __shfl_xor(d, 1);     \
        d += __shfl_xor(d, 2);     \
        d += __shfl_xor(d, 4);     \
        d += __shfl_xor(d, 8);
    RED(t0) RED(t1) RED(t2) RED(t3) RED(t4) RED(t5) RED(t6) RED(t7)
    #undef RED

    if (lane < 8) {
        // static 3-level selects (no runtime register-array indexing)
        #define SEL(x0,x1,x2,x3,x4,x5,x6,x7)                                   \
            ((lane & 4) ? ((lane & 2) ? ((lane & 1) ? x7 : x6)                 \
                                      : ((lane & 1) ? x5 : x4))                \
                        : ((lane & 2) ? ((lane & 1) ? x3 : x2)                 \
                                      : ((lane & 1) ? x1 : x0)))
        const float dj  = SEL(t0, t1, t2, t3, t4, t5, t6, t7);
        const int   sj  = SEL(s0, s1, s2, s3, s4, s5, s6, s7);
        const int   djx = SEL(d0, d1, d2, d3, d4, d5, d6, d7);
        #undef SEL
        const float4 cs = cell_p4[sj];
        const float4 gs = gene_p4[djx];
        res[grp * 8 + lane] =
            make_float2(dj * cs.x * gs.x + cs.y + gs.y, cs.z * gs.z);
    }
}

// ---------------------------------------------------------------------------
// fixup: out[e] = res[rank[e]].
// ---------------------------------------------------------------------------
__global__ __launch_bounds__(256) void fixup_kernel(
    const int*    __restrict__ rank,
    const float2* __restrict__ res,
    float* __restrict__ out)
{
    const int e0 = (blockIdx.x * 256 + threadIdx.x) * 4;
    if (e0 >= N_EDGE) return;
    const int4 r4 = *(const int4*)(rank + e0);
    const float2 r0 = res[r4.x];
    const float2 r1 = res[r4.y];
    const float2 r2 = res[r4.z];
    const float2 r3 = res[r4.w];
    *(float4*)(out + e0)          = make_float4(r0.x, r1.x, r2.x, r3.x);
    *(float4*)(out + N_EDGE + e0) = make_float4(r0.y, r1.y, r2.y, r3.y);
}

// ---------------------------------------------------------------------------
// Fallback (ws too small): unsorted, f32 u vs bf16 proj, no tables.
// ---------------------------------------------------------------------------
__global__ __launch_bounds__(256) void edge_fallback(
    const float*  __restrict__ cell_z,
    const ushort* __restrict__ gene_projb,
    const int*   __restrict__ src_idx,
    const int*   __restrict__ dst_idx,
    const int*   __restrict__ cell_n_id,
    const int*   __restrict__ gene_n_id,
    const float* __restrict__ cell_scale,
    const float* __restrict__ cell_bias,
    const float* __restrict__ cell_std,
    const float* __restrict__ gene_scale,
    const float* __restrict__ gene_bias,
    const float* __restrict__ gene_std,
    float* __restrict__ out)
{
    const int tid  = threadIdx.x;
    const int lane = tid & 15;
    const int e    = blockIdx.x * 16 + (tid >> 4);

    const int s = src_idx[e];
    const int d = dst_idx[e];
    const float4* up = (const float4*)(cell_z + (long)s * DIM);
    const float4 ua = up[2 * lane], ub = up[2 * lane + 1];
    const uint4  v  = ((const uint4*)(gene_projb + (long)d * DIM))[lane];

    float dot = 0.f;
    dot = fmaf(ua.x, __uint_as_float(v.x << 16), dot);
    dot = fmaf(ua.y, __uint_as_float(v.x & 0xffff0000u), dot);
    dot = fmaf(ua.z, __uint_as_float(v.y << 16), dot);
    dot = fmaf(ua.w, __uint_as_float(v.y & 0xffff0000u), dot);
    dot = fmaf(ub.x, __uint_as_float(v.z << 16), dot);
    dot = fmaf(ub.y, __uint_as_float(v.z & 0xffff0000u), dot);
    dot = fmaf(ub.z, __uint_as_float(v.w << 16), dot);
    dot = fmaf(ub.w, __uint_as_float(v.w & 0xffff0000u), dot);

    dot += __shfl_xor(dot, 1);
    dot += __shfl_xor(dot, 2);
    dot += __shfl_xor(dot, 4);
    dot += __shfl_xor(dot, 8);

    if (lane == 0) {
        const int sid = cell_n_id[s];
        const int did = gene_n_id[d];
        out[e]          = dot * cell_scale[sid] * gene_scale[did]
                        + cell_bias[sid] + gene_bias[did];
        out[N_EDGE + e] = cell_std[sid] * gene_std[did];
    }
}

extern "C" void kernel_launch(void* const* d_in, const int* in_sizes, int n_in,
                              void* d_out, int out_size, void* d_ws, size_t ws_size,
                              hipStream_t stream) {
    const float* cell_z     = (const float*)d_in[0];
    const float* gene_z     = (const float*)d_in[1];
    const float* W_gene     = (const float*)d_in[2];
    const float* b_gene     = (const float*)d_in[3];
    const float* cell_scale = (const float*)d_in[4];
    const float* cell_bias  = (const float*)d_in[5];
    const float* cell_std   = (const float*)d_in[6];
    const float* gene_scale = (const float*)d_in[7];
    const float* gene_bias  = (const float*)d_in[8];
    const float* gene_std   = (const float*)d_in[9];
    const int*   src_idx    = (const int*)d_in[10];
    const int*   dst_idx    = (const int*)d_in[11];
    const int*   cell_n_id  = (const int*)d_in[12];
    const int*   gene_n_id  = (const int*)d_in[13];

    // Workspace layout (~49 MB):
    char* ws = (char*)d_ws;
    size_t off = 0;
    ushort* gene_projb = (ushort*)(ws + off); off += (size_t)N_GENE * DIM * 2;  // 5.12 MB
    ushort* Wbt        = (ushort*)(ws + off); off += (size_t)DIM * DIM * 2;     // 32 KB
    const size_t min_need = off;
    ushort* cell_zb    = (ushort*)(ws + off); off += (size_t)N_CELL * DIM * 2;  // 25.6 MB
    float4* cell_p4    = (float4*)(ws + off); off += (size_t)N_CELL * 16;       // 1.6 MB
    float4* gene_p4    = (float4*)(ws + off); off += (size_t)N_GENE * 16;       // 0.32 MB
    unsigned* sorted_p = (unsigned*)(ws + off); off += (size_t)N_EDGE * 4;      // 4 MB
    int*    rank       = (int*)(ws + off);    off += (size_t)N_EDGE * 4;        // 4 MB
    float2* res        = (float2*)(ws + off); off += (size_t)N_EDGE * 8;        // 8 MB
    int*    counts     = (int*)(ws + off);    off += (size_t)NTILE * NBLK_SORT * 4; // 156 KB
    int*    totals     = (int*)(ws + off);    off += 256;

    float* out = (float*)d_out;

    if (ws_size < off) {
        // minimal path: proj only (needs gene_projb + Wbt = 5.15 MB)
        (void)min_need;
        misc_kernel<<<NB_WCAST, 256, 0, stream>>>(
            W_gene, Wbt, cell_n_id, gene_n_id,
            cell_scale, cell_bias, cell_std,
            gene_scale, gene_bias, gene_std, nullptr, nullptr);
        prep_fused<<<NB_PROJ, 256, 0, stream>>>(
            gene_z, b_gene, Wbt, gene_projb,
            cell_z, nullptr, src_idx, dst_idx, nullptr);
        edge_fallback<<<N_EDGE / 16, 256, 0, stream>>>(
            cell_z, gene_projb, src_idx, dst_idx, cell_n_id, gene_n_id,
            cell_scale, cell_bias, cell_std,
            gene_scale, gene_bias, gene_std, out);
        return;
    }

    misc_kernel<<<NB_MISC, 256, 0, stream>>>(
        W_gene, Wbt, cell_n_id, gene_n_id,
        cell_scale, cell_bias, cell_std,
        gene_scale, gene_bias, gene_std, cell_p4, gene_p4);
    prep_fused<<<NB_PREP, 256, 0, stream>>>(
        gene_z, b_gene, Wbt, gene_projb,
        cell_z, (ushort4*)cell_zb, src_idx, dst_idx, counts);
    scanA_kernel<<<NTILE, 256, 0, stream>>>(counts, totals);
    scatter_kernel<<<NBLK_SORT, 256, 0, stream>>>(
        src_idx, dst_idx, counts, totals, sorted_p, rank);
    edge_sorted_kernel<<<NB_EDGE, 256, 0, stream>>>(
        cell_zb, gene_projb, sorted_p, cell_p4, gene_p4, res);
    fixup_kernel<<<(N_EDGE / 4 + 255) / 256, 256, 0, stream>>>(rank, res, out);
}